// Round 11
// baseline (851.608 us; speedup 1.0000x reference)
//
#include <hip/hip_runtime.h>
#include <hip/hip_bf16.h>
#include <math.h>

#define B_TOK 8192
#define D_DIM 1024
#define H_DIM 4096
#define E_NUM 8
#define NPAIR (B_TOK * 2)

typedef __bf16 bf16x8 __attribute__((ext_vector_type(8)));
typedef float f32x4 __attribute__((ext_vector_type(4)));
typedef unsigned short us4 __attribute__((ext_vector_type(4)));

__device__ __forceinline__ unsigned short f2bf(float f) {
  union { float f; unsigned u; } v; v.f = f;
  unsigned r = v.u + 0x7FFFu + ((v.u >> 16) & 1u);
  return (unsigned short)(r >> 16);
}

__device__ __forceinline__ void gload16(const void* g, void* l) {
  __builtin_amdgcn_global_load_lds(
      (const __attribute__((address_space(1))) void*)g,
      (__attribute__((address_space(3))) void*)l, 16, 0, 0);
}

#define BARRIER()    asm volatile("s_barrier" ::: "memory")
#define VM12         asm volatile("s_waitcnt vmcnt(12)" ::: "memory")
#define VM6          asm volatile("s_waitcnt vmcnt(6)" ::: "memory")
#define VM0          asm volatile("s_waitcnt vmcnt(0)" ::: "memory")
#define LGKM0        asm volatile("s_waitcnt lgkmcnt(0)" ::: "memory")
#define RF(x) __builtin_amdgcn_readfirstlane(x)

// ---------------- x fp32 -> bf16 ----------------
__global__ void k_convert_x(const float* __restrict__ x, unsigned short* __restrict__ xb) {
  int i = (blockIdx.x * 256 + threadIdx.x) * 4;
  float4 v = *(const float4*)(x + i);
  us4 o;
  o[0] = f2bf(v.x); o[1] = f2bf(v.y); o[2] = f2bf(v.z); o[3] = f2bf(v.w);
  *(us4*)(xb + i) = o;
}

// ---- fused weight prep: w1 (E,D,H) -> w1t (E,H,D) bf16; w2 (E,H,D) -> w2t (E,D,H) ----
__global__ void k_prep_w(const float* __restrict__ w1, const float* __restrict__ w2,
                         unsigned short* __restrict__ w1t, unsigned short* __restrict__ w2t) {
  __shared__ float t[32][33];
  int b = blockIdx.x;
  int which = b >> 15;          // 0: w1, 1: w2
  int lb = b & 32767;
  int e = lb >> 12;
  int local = lb & 4095;
  int rows = which ? H_DIM : D_DIM;   // input rows
  int cols = which ? D_DIM : H_DIM;   // input cols
  int xt = which ? (local & 31) : (local & 127);
  int yt = which ? (local >> 5) : (local >> 7);
  const float* ine = (which ? w2 : w1) + (size_t)e * D_DIM * H_DIM;
  unsigned short* oute = (which ? w2t : w1t) + (size_t)e * D_DIM * H_DIM;
  int c0 = xt * 32, r0 = yt * 32;
  int tx = threadIdx.x, ty = threadIdx.y;
#pragma unroll
  for (int j = 0; j < 32; j += 8)
    t[ty + j][tx] = ine[(size_t)(r0 + ty + j) * cols + c0 + tx];
  __syncthreads();
#pragma unroll
  for (int j = 0; j < 32; j += 8)
    oute[(size_t)(c0 + ty + j) * rows + r0 + tx] = f2bf(t[tx][ty + j]);
}

// ---------------- router: logits, top-2, softmax ----------------
__global__ void k_router(const float* __restrict__ x, const float* __restrict__ wg,
                         const float* __restrict__ bg, int* __restrict__ tidx,
                         float* __restrict__ tgate, int* __restrict__ cnt) {
  int wid = threadIdx.x >> 6, lane = threadIdx.x & 63;
  int t = blockIdx.x * 4 + wid;
  float acc[E_NUM];
#pragma unroll
  for (int e = 0; e < E_NUM; e++) acc[e] = 0.f;
  const float* xr = x + (size_t)t * D_DIM;
  for (int i = lane; i < D_DIM; i += 64) {
    float xv = xr[i];
#pragma unroll
    for (int e = 0; e < E_NUM; e++) acc[e] += xv * wg[e * D_DIM + i];
  }
#pragma unroll
  for (int e = 0; e < E_NUM; e++) {
#pragma unroll
    for (int off = 32; off; off >>= 1) acc[e] += __shfl_xor(acc[e], off);
  }
  if (lane == 0) {
    float v[E_NUM];
#pragma unroll
    for (int e = 0; e < E_NUM; e++) v[e] = acc[e] + bg[e];
    int i0 = 0; float v0 = v[0];
#pragma unroll
    for (int e = 1; e < E_NUM; e++) if (v[e] > v0) { v0 = v[e]; i0 = e; }
    int i1 = -1; float v1 = -1e30f;
#pragma unroll
    for (int e = 0; e < E_NUM; e++) if (e != i0 && v[e] > v1) { v1 = v[e]; i1 = e; }
    float g0 = 1.f / (1.f + expf(v1 - v0));
    float g1 = 1.f - g0;
    tidx[2 * t] = i0; tidx[2 * t + 1] = i1;
    tgate[2 * t] = g0; tgate[2 * t + 1] = g1;
    atomicAdd(cnt + i0, 1);
    atomicAdd(cnt + i1, 1);
  }
}

// meta: cnt[8] @0 | eoff[9] @8 | cursor[8] @17 | toff1[9] @25 | toff2[9] @34
__global__ void k_prefix(int* __restrict__ meta) {
  if (threadIdx.x == 0) {
    int* cnt = meta;
    int* eoff = meta + 8;
    int* cursor = meta + 17;
    int* toff1 = meta + 25;
    int* toff2 = meta + 34;
    int a = 0, t1 = 0, t2 = 0;
    for (int e = 0; e < E_NUM; e++) {
      eoff[e] = a; cursor[e] = a; a += cnt[e];
      toff1[e] = t1; toff2[e] = t2;
      int mc = (cnt[e] + 255) >> 8;   // ceil(cnt/256) live M-tiles (256-row)
      t1 += mc * (H_DIM / 128);
      t2 += mc * (D_DIM / 128);
    }
    eoff[E_NUM] = a; toff1[E_NUM] = t1; toff2[E_NUM] = t2;
  }
}

__global__ void k_scatter(const int* __restrict__ tidx, const float* __restrict__ tgate,
                          int* __restrict__ cursor, int* __restrict__ ptok,
                          float* __restrict__ pgate) {
  int t = blockIdx.x * 256 + threadIdx.x;
#pragma unroll
  for (int k = 0; k < 2; k++) {
    int e = tidx[2 * t + k];
    int p = atomicAdd(cursor + e, 1);
    ptok[p] = t;
    pgate[p] = tgate[2 * t + k];
  }
}

// -- grouped GEMM, 256x128 tile, wave=128x64, BK=32, depth-3 ring -----------
// LDS-traffic optimization: 12 ds_read_b128 feed 32 MFMA per wave-step
// (vs 8:16 at 64x64 wave) -> 1.5x FLOP per LDS byte. LDS = 3 bufs x
// (A 256x32 + B 128x32) bf16 = 72 KB -> 2 blocks/CU. Seg-swizzle
// slot[row][s] = data[row][s ^ ((row>>1)&3)] via pre-swizzled global source
// (0 bank conflicts measured R3-R10). Per K-step (buf = kt%3, 6 loads/wave):
// vmcnt(12) -> barrier -> 12 frag ds_reads -> lgkm0 -> barrier (WAR) ->
// STAGE(kt+3) -> setprio(1) 32 MFMA setprio(0). 18 loads in flight steady.
// Compacted tile list: grid = worst-case live tiles, decode via toff prefix.
// MODE 1: A = xb gathered via ptok, out = relu(A@B^T + b1) -> Hbuf (bf16)
// MODE 2: A = Hbuf rows direct,   out = (A@B^T + b2)*gate atomicAdd-> Out
template <int KDIM, int NDIM, int MODE>
__global__ __launch_bounds__(256, 2) void k_gemm(
    const unsigned short* __restrict__ A, const unsigned short* __restrict__ Bt,
    const float* __restrict__ bias, const int* __restrict__ meta,
    const int* __restrict__ ptok, const float* __restrict__ pgate,
    unsigned short* __restrict__ Hout, float* __restrict__ Out) {
  constexpr int NT = NDIM / 128;
  constexpr int NKT = KDIM / 32;
  static_assert(NKT % 3 == 2 && NKT >= 8, "tail pattern requires NKT==2 mod 3");
  const int* eoff = meta + 8;
  const int* toff = (MODE == 1) ? (meta + 25) : (meta + 34);

  // prefix in SGPRs
  int tf[E_NUM + 1];
#pragma unroll
  for (int q = 0; q <= E_NUM; q++) tf[q] = RF(toff[q]);

  int nwg = gridDim.x;
  int bid = blockIdx.x;
  int i = (bid & 7) * (nwg >> 3) + (bid >> 3);  // XCD chunk swizzle (nwg%8==0)
  if (i >= tf[E_NUM]) return;                   // few trailing dead tiles
  int e = 0;
#pragma unroll
  for (int q = 1; q < E_NUM; q++) e += (i >= tf[q]);
  int r = i - tf[e];
  int mt = r / NT;
  int nt = r - mt * NT;
  int off = RF(eoff[e]);
  int cnt = RF(eoff[e + 1]) - off;
  int m0 = mt * 256;                            // m0 < cnt by construction

  // [3 bufs][ A 256x32 (8192) | B 128x32 (4096) ] shorts = 72 KB
  __shared__ unsigned short lds[3][8192 + 4096];

  int tid = threadIdx.x;
  int w = tid >> 6, lane = tid & 63;
  int wm = w >> 1, wn = w & 1;  // 2x2 wave grid; per-wave output 128x64

  // staging: A chunk q = w*4 + c (c 0..3) covers rows q*16..q*16+15;
  //          B chunk q = w*2 + c (c 0..1). lane -> row q*16+(lane>>2),
  // slot seg (lane&3); LDS short-offset q*512 + lane*8.
  // Pre-swizzled global seg: (lane&3) ^ ((row>>1)&3) = (lane&3)^((lane>>3)&3).
  int sseg = (lane & 3) ^ ((lane >> 3) & 3);
  const unsigned short* aSrc[4];
  const unsigned short* bSrc[2];
#pragma unroll
  for (int c = 0; c < 4; c++) {
    int q = w * 4 + c;
    int lrow = q * 16 + (lane >> 2);
    int arow = m0 + lrow;
    int ar = (arow < cnt) ? arow : (cnt - 1);
    size_t grow;
    if (MODE == 1) grow = (size_t)ptok[off + ar];
    else grow = (size_t)(off + ar);
    aSrc[c] = A + grow * KDIM + sseg * 8;
  }
#pragma unroll
  for (int c = 0; c < 2; c++) {
    int q = w * 2 + c;
    int nrow = nt * 128 + q * 16 + (lane >> 2);
    bSrc[c] = Bt + (size_t)e * NDIM * KDIM + (size_t)nrow * KDIM + sseg * 8;
  }

  // frag reads: row = base + (lane&15); wanted seg = lane>>4;
  // slot seg' = (lane>>4) ^ ((row>>1)&3) = (lane>>4) ^ ((lane>>1)&3).
  int segp = (lane >> 4) ^ ((lane >> 1) & 3);
  f32x4 acc[8][4] = {};

#define STAGE(buf, k0)                                              \
  {                                                                 \
    _Pragma("unroll")                                               \
    for (int c = 0; c < 4; c++)                                     \
      gload16(aSrc[c] + (k0), &lds[buf][(w * 4 + c) * 512]);        \
    _Pragma("unroll")                                               \
    for (int c = 0; c < 2; c++)                                     \
      gload16(bSrc[c] + (k0), &lds[buf][8192 + (w * 2 + c) * 512]); \
  }
#define NOSTG ((void)0)

#define STEP(buf, WAITC, STGC)                                              \
  {                                                                         \
    WAITC; BARRIER();                                                       \
    bf16x8 aF[8], bF[4];                                                    \
    _Pragma("unroll")                                                       \
    for (int m = 0; m < 8; m++) {                                           \
      int row = wm * 128 + m * 16 + (lane & 15);                            \
      aF[m] = *(const bf16x8*)&lds[buf][row * 32 + segp * 8];               \
    }                                                                       \
    _Pragma("unroll")                                                       \
    for (int n = 0; n < 4; n++) {                                           \
      int row = wn * 64 + n * 16 + (lane & 15);                             \
      bF[n] = *(const bf16x8*)&lds[buf][8192 + row * 32 + segp * 8];        \
    }                                                                       \
    LGKM0; BARRIER();                                                       \
    STGC;                                                                   \
    __builtin_amdgcn_s_setprio(1);                                          \
    _Pragma("unroll")                                                       \
    for (int m = 0; m < 8; m++)                                             \
      _Pragma("unroll")                                                     \
      for (int n = 0; n < 4; n++)                                           \
        acc[m][n] =                                                         \
            __builtin_amdgcn_mfma_f32_16x16x32_bf16(aF[m], bF[n], acc[m][n], 0, 0, 0); \
    __builtin_amdgcn_s_setprio(0);                                          \
  }

  // prologue: 3 K-steps in flight (18 loads per thread)
  STAGE(0, 0);
  STAGE(1, 32);
  STAGE(2, 64);

#pragma unroll 1
  for (int kt = 0; kt < NKT - 5; kt += 3) {
    STEP(0, VM12, STAGE(0, (kt + 3) * 32));
    STEP(1, VM12, STAGE(1, (kt + 4) * 32));
    STEP(2, VM12, STAGE(2, (kt + 5) * 32));
  }
  // tail: steps NKT-5 .. NKT-1 (NKT-5 == 0 mod 3)
  STEP(0, VM12, STAGE(0, (NKT - 2) * 32));
  STEP(1, VM12, STAGE(1, (NKT - 1) * 32));
  STEP(2, VM12, NOSTG);
  STEP(0, VM6, NOSTG);
  STEP(1, VM0, NOSTG);

#undef STAGE
#undef NOSTG
#undef STEP

  // epilogue: C/D map col=lane&15, row=(lane>>4)*4+r
#pragma unroll
  for (int m = 0; m < 8; m++) {
    int lrowb = wm * 128 + m * 16 + (lane >> 4) * 4;
#pragma unroll
    for (int r2 = 0; r2 < 4; r2++) {
      int arow = m0 + lrowb + r2;
      if (arow < cnt) {
        if constexpr (MODE == 1) {
          size_t rowbase = (size_t)(off + arow) * NDIM;
#pragma unroll
          for (int n = 0; n < 4; n++) {
            int col = nt * 128 + wn * 64 + n * 16 + (lane & 15);
            float v = acc[m][n][r2] + bias[e * NDIM + col];
            v = v > 0.f ? v : 0.f;
            Hout[rowbase + col] = f2bf(v);
          }
        } else {
          int tok = ptok[off + arow];
          float g = pgate[off + arow];
#pragma unroll
          for (int n = 0; n < 4; n++) {
            int col = nt * 128 + wn * 64 + n * 16 + (lane & 15);
            float v = (acc[m][n][r2] + bias[e * NDIM + col]) * g;
            atomicAdd(Out + (size_t)tok * D_DIM + col, v);
          }
        }
      }
    }
  }
}

extern "C" void kernel_launch(void* const* d_in, const int* in_sizes, int n_in,
                              void* d_out, int out_size, void* d_ws, size_t ws_size,
                              hipStream_t stream) {
  const float* x  = (const float*)d_in[0];
  const float* wg = (const float*)d_in[1];
  const float* bg = (const float*)d_in[2];
  const float* w1 = (const float*)d_in[3];
  const float* b1 = (const float*)d_in[4];
  const float* w2 = (const float*)d_in[5];
  const float* b2 = (const float*)d_in[6];
  float* out = (float*)d_out;

  char* ws = (char*)d_ws;
  unsigned short* xb = (unsigned short*)ws;   ws += (size_t)B_TOK * D_DIM * 2;
  unsigned short* w1t = (unsigned short*)ws;  ws += (size_t)E_NUM * D_DIM * H_DIM * 2;
  unsigned short* w2t = (unsigned short*)ws;  ws += (size_t)E_NUM * D_DIM * H_DIM * 2;
  unsigned short* Hbuf = (unsigned short*)ws; ws += (size_t)NPAIR * H_DIM * 2;
  int* tidx = (int*)ws;    ws += (size_t)NPAIR * 4;
  float* tgate = (float*)ws; ws += (size_t)NPAIR * 4;
  int* ptok = (int*)ws;    ws += (size_t)NPAIR * 4;
  float* pgate = (float*)ws; ws += (size_t)NPAIR * 4;
  int* meta = (int*)ws;  // cnt[8] | eoff[9] | cursor[8] | toff1[9] | toff2[9]
  int* cnt = meta;
  int* cursor = meta + 17;

  hipMemsetAsync(meta, 0, 64 * sizeof(int), stream);
  hipMemsetAsync(out, 0, (size_t)out_size * sizeof(float), stream);

  k_convert_x<<<(B_TOK * D_DIM) / 1024, 256, 0, stream>>>(x, xb);
  k_prep_w<<<2 * E_NUM * 4096, dim3(32, 8), 0, stream>>>(w1, w2, w1t, w2t);
  k_router<<<B_TOK / 4, 256, 0, stream>>>(x, wg, bg, tidx, tgate, cnt);
  k_prefix<<<1, 64, 0, stream>>>(meta);
  k_scatter<<<B_TOK / 256, 256, 0, stream>>>(tidx, tgate, cursor, ptok, pgate);
  // worst-case compact grids (host consts, both divisible by 8):
  // G1 = (NPAIR/256 + E) * (H/128) = 72*32 = 2304
  // G2 = (NPAIR/256 + E) * (D/128) = 72*8  = 576
  k_gemm<D_DIM, H_DIM, 1><<<(NPAIR / 256 + E_NUM) * (H_DIM / 128), 256, 0, stream>>>(
      xb, w1t, b1, meta, ptok, pgate, Hbuf, nullptr);
  k_gemm<H_DIM, D_DIM, 2><<<(NPAIR / 256 + E_NUM) * (D_DIM / 128), 256, 0, stream>>>(
      Hbuf, w2t, b2, meta, ptok, pgate, nullptr, out);
}

// Round 12
// 846.538 us; speedup vs baseline: 1.0060x; 1.0060x over previous
//
#include <hip/hip_runtime.h>
#include <hip/hip_bf16.h>
#include <math.h>

#define B_TOK 8192
#define D_DIM 1024
#define H_DIM 4096
#define E_NUM 8
#define NPAIR (B_TOK * 2)

typedef __bf16 bf16x8 __attribute__((ext_vector_type(8)));
typedef float f32x4 __attribute__((ext_vector_type(4)));
typedef unsigned short us4 __attribute__((ext_vector_type(4)));

__device__ __forceinline__ unsigned short f2bf(float f) {
  union { float f; unsigned u; } v; v.f = f;
  unsigned r = v.u + 0x7FFFu + ((v.u >> 16) & 1u);
  return (unsigned short)(r >> 16);
}

__device__ __forceinline__ void gload16(const void* g, void* l) {
  __builtin_amdgcn_global_load_lds(
      (const __attribute__((address_space(1))) void*)g,
      (__attribute__((address_space(3))) void*)l, 16, 0, 0);
}

#define BARRIER()    asm volatile("s_barrier" ::: "memory")
#define VM6          asm volatile("s_waitcnt vmcnt(6)" ::: "memory")
#define VM0          asm volatile("s_waitcnt vmcnt(0)" ::: "memory")
#define LGKM0        asm volatile("s_waitcnt lgkmcnt(0)" ::: "memory")
#define RF(x) __builtin_amdgcn_readfirstlane(x)

// ---- fused prep: router [0,2048) | x->bf16 [2048,10240) | w-transp [10240,75776) ----
__global__ void k_prep(const float* __restrict__ x, unsigned short* __restrict__ xb,
                       const float* __restrict__ w1, const float* __restrict__ w2,
                       unsigned short* __restrict__ w1t, unsigned short* __restrict__ w2t,
                       const float* __restrict__ wg, const float* __restrict__ bg,
                       int* __restrict__ tidx, float* __restrict__ tgate,
                       int* __restrict__ cnt) {
  __shared__ float t[32][33];
  int b = blockIdx.x;
  int tid = threadIdx.x;
  if (b < 2048) {
    // ---- router: 4 tokens per block ----
    int wid = tid >> 6, lane = tid & 63;
    int tok = b * 4 + wid;
    float acc[E_NUM];
#pragma unroll
    for (int e = 0; e < E_NUM; e++) acc[e] = 0.f;
    const float* xr = x + (size_t)tok * D_DIM;
    for (int i = lane; i < D_DIM; i += 64) {
      float xv = xr[i];
#pragma unroll
      for (int e = 0; e < E_NUM; e++) acc[e] += xv * wg[e * D_DIM + i];
    }
#pragma unroll
    for (int e = 0; e < E_NUM; e++) {
#pragma unroll
      for (int off = 32; off; off >>= 1) acc[e] += __shfl_xor(acc[e], off);
    }
    if (lane == 0) {
      float v[E_NUM];
#pragma unroll
      for (int e = 0; e < E_NUM; e++) v[e] = acc[e] + bg[e];
      int i0 = 0; float v0 = v[0];
#pragma unroll
      for (int e = 1; e < E_NUM; e++) if (v[e] > v0) { v0 = v[e]; i0 = e; }
      int i1 = -1; float v1 = -1e30f;
#pragma unroll
      for (int e = 0; e < E_NUM; e++) if (e != i0 && v[e] > v1) { v1 = v[e]; i1 = e; }
      float g0 = 1.f / (1.f + expf(v1 - v0));
      float g1 = 1.f - g0;
      tidx[2 * tok] = i0; tidx[2 * tok + 1] = i1;
      tgate[2 * tok] = g0; tgate[2 * tok + 1] = g1;
      atomicAdd(cnt + i0, 1);
      atomicAdd(cnt + i1, 1);
    }
  } else if (b < 10240) {
    // ---- x fp32 -> bf16 ----
    int i = ((b - 2048) * 256 + tid) * 4;
    float4 v = *(const float4*)(x + i);
    us4 o;
    o[0] = f2bf(v.x); o[1] = f2bf(v.y); o[2] = f2bf(v.z); o[3] = f2bf(v.w);
    *(us4*)(xb + i) = o;
  } else {
    // ---- weight transpose: w1 (E,D,H)->(E,H,D), w2 (E,H,D)->(E,D,H), bf16 ----
    int lb = b - 10240;
    int which = lb >> 15;          // 0: w1 (32768 blocks), 1: w2
    lb &= 32767;
    int e = lb >> 12;
    int local = lb & 4095;
    int rows = which ? H_DIM : D_DIM;
    int cols = which ? D_DIM : H_DIM;
    int xt = which ? (local & 31) : (local & 127);
    int yt = which ? (local >> 5) : (local >> 7);
    const float* ine = (which ? w2 : w1) + (size_t)e * D_DIM * H_DIM;
    unsigned short* oute = (which ? w2t : w1t) + (size_t)e * D_DIM * H_DIM;
    int c0 = xt * 32, r0 = yt * 32;
    int tx = tid & 31, ty = tid >> 5;  // 32 x 8
#pragma unroll
    for (int j = 0; j < 32; j += 8)
      t[ty + j][tx] = ine[(size_t)(r0 + ty + j) * cols + c0 + tx];
    __syncthreads();
#pragma unroll
    for (int j = 0; j < 32; j += 8)
      oute[(size_t)(c0 + ty + j) * rows + r0 + tx] = f2bf(t[tx][ty + j]);
  }
}

// meta: cnt[8] @0 | eoff[9] @8 | cursor[8] @17 | toff1[9] @25 | toff2[9] @34
__global__ void k_prefix(int* __restrict__ meta) {
  if (threadIdx.x == 0) {
    int* cnt = meta;
    int* eoff = meta + 8;
    int* cursor = meta + 17;
    int* toff1 = meta + 25;
    int* toff2 = meta + 34;
    int a = 0, t1 = 0, t2 = 0;
    for (int e = 0; e < E_NUM; e++) {
      eoff[e] = a; cursor[e] = a; a += cnt[e];
      toff1[e] = t1; toff2[e] = t2;
      int mc = (cnt[e] + 255) >> 8;   // ceil(cnt/256): 256-row M-tiles
      t1 += mc * (H_DIM / 128);
      t2 += mc * (D_DIM / 128);
    }
    eoff[E_NUM] = a; toff1[E_NUM] = t1; toff2[E_NUM] = t2;
  }
}

__global__ void k_scatter(const int* __restrict__ tidx, const float* __restrict__ tgate,
                          int* __restrict__ cursor, int* __restrict__ ptok,
                          float* __restrict__ pgate) {
  int t = blockIdx.x * 256 + threadIdx.x;
#pragma unroll
  for (int k = 0; k < 2; k++) {
    int e = tidx[2 * t + k];
    int p = atomicAdd(cursor + e, 1);
    ptok[p] = t;
    pgate[p] = tgate[2 * t + k];
  }
}

// -- grouped GEMM, 256x128 tile, wave=128x64, BK=32, depth-2, m-split step ---
// Goal: 1.5x FLOP per LDS byte (12 ds_read feed 32 MFMA per wave-step) AND
// 2 blocks/CU (R11 failed at 124 VGPR + 128 AGPR ~ 256). Diet: depth-2 LDS
// (2 x 24 KB = 48 KB) and m-split step so only bF[4]+aG[4] (32 VGPR) live at
// the WAR barrier:
//   vmcnt(6) -> barrier -> bF[4]+aF[4](m0-3) reads -> 16 MFMA ->
//   aG[4](m4-7) reads -> lgkm0 -> barrier -> STAGE(t+2) -> 16 MFMA (aG)
// Seg-swizzle slot[row][s] = data[row][s ^ ((row>>1)&3)] via pre-swizzled
// global source (0 conflicts, R3-R11). Compacted tile list via toff prefix.
// MODE 1: A = xb gathered via ptok, out = relu(A@B^T + b1) -> Hbuf (bf16)
// MODE 2: A = Hbuf rows direct,   out = (A@B^T + b2)*gate atomicAdd-> Out
template <int KDIM, int NDIM, int MODE>
__global__ __launch_bounds__(256, 2) void k_gemm(
    const unsigned short* __restrict__ A, const unsigned short* __restrict__ Bt,
    const float* __restrict__ bias, const int* __restrict__ meta,
    const int* __restrict__ ptok, const float* __restrict__ pgate,
    unsigned short* __restrict__ Hout, float* __restrict__ Out) {
  constexpr int NT = NDIM / 128;
  constexpr int NKT = KDIM / 32;
  static_assert(NKT % 2 == 0 && NKT >= 4, "even NKT");
  const int* eoff = meta + 8;
  const int* toff = (MODE == 1) ? (meta + 25) : (meta + 34);

  int tf[E_NUM + 1];
#pragma unroll
  for (int q = 0; q <= E_NUM; q++) tf[q] = RF(toff[q]);

  int nwg = gridDim.x;
  int bid = blockIdx.x;
  int i = (bid & 7) * (nwg >> 3) + (bid >> 3);  // XCD chunk swizzle (nwg%8==0)
  if (i >= tf[E_NUM]) return;
  int e = 0;
#pragma unroll
  for (int q = 1; q < E_NUM; q++) e += (i >= tf[q]);
  int r = i - tf[e];
  int mt = r / NT;
  int nt = r - mt * NT;
  int off = RF(eoff[e]);
  int cnt = RF(eoff[e + 1]) - off;
  int m0 = mt * 256;                            // m0 < cnt by construction

  // [2 bufs][ A 256x32 (8192 sh) | B 128x32 (4096 sh) ] = 48 KB
  __shared__ unsigned short lds[2][8192 + 4096];

  int tid = threadIdx.x;
  int w = tid >> 6, lane = tid & 63;
  int wm = w >> 1, wn = w & 1;  // 2x2 wave grid; per-wave output 128x64

  // staging: A chunk q=w*4+c rows q*16..+15; B chunk q=w*2+c. lane -> row
  // q*16+(lane>>2), slot seg lane&3, LDS short-off q*512+lane*8.
  // Pre-swizzled global seg = (lane&3) ^ ((row>>1)&3) = (lane&3)^((lane>>3)&3).
  int sseg = (lane & 3) ^ ((lane >> 3) & 3);
  const unsigned short* aSrc[4];
  const unsigned short* bSrc[2];
#pragma unroll
  for (int c = 0; c < 4; c++) {
    int q = w * 4 + c;
    int arow = m0 + q * 16 + (lane >> 2);
    int ar = (arow < cnt) ? arow : (cnt - 1);
    size_t grow;
    if (MODE == 1) grow = (size_t)ptok[off + ar];
    else grow = (size_t)(off + ar);
    aSrc[c] = A + grow * KDIM + sseg * 8;
  }
#pragma unroll
  for (int c = 0; c < 2; c++) {
    int q = w * 2 + c;
    int nrow = nt * 128 + q * 16 + (lane >> 2);
    bSrc[c] = Bt + (size_t)e * NDIM * KDIM + (size_t)nrow * KDIM + sseg * 8;
  }

  // frag reads: row = base + (lane&15); slot seg' = (lane>>4) ^ ((lane>>1)&3)
  int segp = (lane >> 4) ^ ((lane >> 1) & 3);
  f32x4 acc[8][4] = {};

#define STAGE(buf, k0)                                              \
  {                                                                 \
    _Pragma("unroll")                                               \
    for (int c = 0; c < 4; c++)                                     \
      gload16(aSrc[c] + (k0), &lds[buf][(w * 4 + c) * 512]);        \
    _Pragma("unroll")                                               \
    for (int c = 0; c < 2; c++)                                     \
      gload16(bSrc[c] + (k0), &lds[buf][8192 + (w * 2 + c) * 512]); \
  }
#define NOSTG ((void)0)

#define STEP(buf, WAITC, STGC)                                              \
  {                                                                         \
    WAITC; BARRIER();                                                       \
    bf16x8 bF[4], aF[4];                                                    \
    _Pragma("unroll")                                                       \
    for (int n = 0; n < 4; n++) {                                           \
      int row = wn * 64 + n * 16 + (lane & 15);                             \
      bF[n] = *(const bf16x8*)&lds[buf][8192 + row * 32 + segp * 8];        \
    }                                                                       \
    _Pragma("unroll")                                                       \
    for (int m = 0; m < 4; m++) {                                           \
      int row = wm * 128 + m * 16 + (lane & 15);                            \
      aF[m] = *(const bf16x8*)&lds[buf][row * 32 + segp * 8];               \
    }                                                                       \
    __builtin_amdgcn_s_setprio(1);                                          \
    _Pragma("unroll")                                                       \
    for (int m = 0; m < 4; m++)                                             \
      _Pragma("unroll")                                                     \
      for (int n = 0; n < 4; n++)                                           \
        acc[m][n] =                                                         \
            __builtin_amdgcn_mfma_f32_16x16x32_bf16(aF[m], bF[n], acc[m][n], 0, 0, 0); \
    __builtin_amdgcn_s_setprio(0);                                          \
    bf16x8 aG[4];                                                           \
    _Pragma("unroll")                                                       \
    for (int m = 0; m < 4; m++) {                                           \
      int row = wm * 128 + (m + 4) * 16 + (lane & 15);                      \
      aG[m] = *(const bf16x8*)&lds[buf][row * 32 + segp * 8];               \
    }                                                                       \
    LGKM0; BARRIER();                                                       \
    STGC;                                                                   \
    __builtin_amdgcn_s_setprio(1);                                          \
    _Pragma("unroll")                                                       \
    for (int m = 0; m < 4; m++)                                             \
      _Pragma("unroll")                                                     \
      for (int n = 0; n < 4; n++)                                           \
        acc[m + 4][n] =                                                     \
            __builtin_amdgcn_mfma_f32_16x16x32_bf16(aG[m], bF[n], acc[m + 4][n], 0, 0, 0); \
    __builtin_amdgcn_s_setprio(0);                                          \
  }

  // prologue: 2 K-steps in flight (12 loads per thread)
  STAGE(0, 0);
  STAGE(1, 32);

#pragma unroll 1
  for (int kt = 0; kt < NKT - 2; kt += 2) {
    STEP(0, VM6, STAGE(0, (kt + 2) * 32));
    STEP(1, VM6, STAGE(1, (kt + 3) * 32));
  }
  STEP(0, VM6, NOSTG);
  STEP(1, VM0, NOSTG);

#undef STAGE
#undef NOSTG
#undef STEP

  // epilogue: C/D map col=lane&15, row=(lane>>4)*4+r
#pragma unroll
  for (int m = 0; m < 8; m++) {
    int lrowb = wm * 128 + m * 16 + (lane >> 4) * 4;
#pragma unroll
    for (int r2 = 0; r2 < 4; r2++) {
      int arow = m0 + lrowb + r2;
      if (arow < cnt) {
        if constexpr (MODE == 1) {
          size_t rowbase = (size_t)(off + arow) * NDIM;
#pragma unroll
          for (int n = 0; n < 4; n++) {
            int col = nt * 128 + wn * 64 + n * 16 + (lane & 15);
            float v = acc[m][n][r2] + bias[e * NDIM + col];
            v = v > 0.f ? v : 0.f;
            Hout[rowbase + col] = f2bf(v);
          }
        } else {
          int tok = ptok[off + arow];
          float g = pgate[off + arow];
#pragma unroll
          for (int n = 0; n < 4; n++) {
            int col = nt * 128 + wn * 64 + n * 16 + (lane & 15);
            float v = (acc[m][n][r2] + bias[e * NDIM + col]) * g;
            atomicAdd(Out + (size_t)tok * D_DIM + col, v);
          }
        }
      }
    }
  }
}

extern "C" void kernel_launch(void* const* d_in, const int* in_sizes, int n_in,
                              void* d_out, int out_size, void* d_ws, size_t ws_size,
                              hipStream_t stream) {
  const float* x  = (const float*)d_in[0];
  const float* wg = (const float*)d_in[1];
  const float* bg = (const float*)d_in[2];
  const float* w1 = (const float*)d_in[3];
  const float* b1 = (const float*)d_in[4];
  const float* w2 = (const float*)d_in[5];
  const float* b2 = (const float*)d_in[6];
  float* out = (float*)d_out;

  char* ws = (char*)d_ws;
  unsigned short* xb = (unsigned short*)ws;   ws += (size_t)B_TOK * D_DIM * 2;
  unsigned short* w1t = (unsigned short*)ws;  ws += (size_t)E_NUM * D_DIM * H_DIM * 2;
  unsigned short* w2t = (unsigned short*)ws;  ws += (size_t)E_NUM * D_DIM * H_DIM * 2;
  unsigned short* Hbuf = (unsigned short*)ws; ws += (size_t)NPAIR * H_DIM * 2;
  int* tidx = (int*)ws;    ws += (size_t)NPAIR * 4;
  float* tgate = (float*)ws; ws += (size_t)NPAIR * 4;
  int* ptok = (int*)ws;    ws += (size_t)NPAIR * 4;
  float* pgate = (float*)ws; ws += (size_t)NPAIR * 4;
  int* meta = (int*)ws;  // cnt[8] | eoff[9] | cursor[8] | toff1[9] | toff2[9]
  int* cursor = meta + 17;

  hipMemsetAsync(meta, 0, 64 * sizeof(int), stream);
  hipMemsetAsync(out, 0, (size_t)out_size * sizeof(float), stream);

  // fused prep: router (2048) + convert_x (8192) + w transposes (65536)
  k_prep<<<2048 + 8192 + 65536, 256, 0, stream>>>(
      x, xb, w1, w2, w1t, w2t, wg, bg, tidx, tgate, meta);
  k_prefix<<<1, 64, 0, stream>>>(meta);
  k_scatter<<<B_TOK / 256, 256, 0, stream>>>(tidx, tgate, cursor, ptok, pgate);
  // worst-case compact grids (host consts, divisible by 8):
  // G1 = (NPAIR/256 + E) * (H/128) = 72*32 = 2304
  // G2 = (NPAIR/256 + E) * (D/128) = 72*8  = 576
  k_gemm<D_DIM, H_DIM, 1><<<(NPAIR / 256 + E_NUM) * (H_DIM / 128), 256, 0, stream>>>(
      xb, w1t, b1, meta, ptok, pgate, Hbuf, nullptr);
  k_gemm<H_DIM, D_DIM, 2><<<(NPAIR / 256 + E_NUM) * (D_DIM / 128), 256, 0, stream>>>(
      Hbuf, w2t, b2, meta, ptok, pgate, nullptr, out);
}

// Round 13
// 814.684 us; speedup vs baseline: 1.0453x; 1.0391x over previous
//
#include <hip/hip_runtime.h>
#include <hip/hip_bf16.h>
#include <math.h>

#define B_TOK 8192
#define D_DIM 1024
#define H_DIM 4096
#define E_NUM 8
#define NPAIR (B_TOK * 2)

typedef __bf16 bf16x8 __attribute__((ext_vector_type(8)));
typedef float f32x4 __attribute__((ext_vector_type(4)));
typedef unsigned short us4 __attribute__((ext_vector_type(4)));

__device__ __forceinline__ unsigned short f2bf(float f) {
  union { float f; unsigned u; } v; v.f = f;
  unsigned r = v.u + 0x7FFFu + ((v.u >> 16) & 1u);
  return (unsigned short)(r >> 16);
}

__device__ __forceinline__ void gload16(const void* g, void* l) {
  __builtin_amdgcn_global_load_lds(
      (const __attribute__((address_space(1))) void*)g,
      (__attribute__((address_space(3))) void*)l, 16, 0, 0);
}

#define BARRIER()    asm volatile("s_barrier" ::: "memory")
#define VM4          asm volatile("s_waitcnt vmcnt(4)" ::: "memory")
#define VM0          asm volatile("s_waitcnt vmcnt(0)" ::: "memory")
#define LGKM0        asm volatile("s_waitcnt lgkmcnt(0)" ::: "memory")
#define RF(x) __builtin_amdgcn_readfirstlane(x)

// ---- fused prep: router [0,2048) | x->bf16 [2048,10240) | w-transp [10240,75776) ----
__global__ void k_prep(const float* __restrict__ x, unsigned short* __restrict__ xb,
                       const float* __restrict__ w1, const float* __restrict__ w2,
                       unsigned short* __restrict__ w1t, unsigned short* __restrict__ w2t,
                       const float* __restrict__ wg, const float* __restrict__ bg,
                       int* __restrict__ tidx, float* __restrict__ tgate,
                       int* __restrict__ cnt) {
  __shared__ float t[32][33];
  int b = blockIdx.x;
  int tid = threadIdx.x;
  if (b < 2048) {
    // ---- router: 4 tokens per block ----
    int wid = tid >> 6, lane = tid & 63;
    int tok = b * 4 + wid;
    float acc[E_NUM];
#pragma unroll
    for (int e = 0; e < E_NUM; e++) acc[e] = 0.f;
    const float* xr = x + (size_t)tok * D_DIM;
    for (int i = lane; i < D_DIM; i += 64) {
      float xv = xr[i];
#pragma unroll
      for (int e = 0; e < E_NUM; e++) acc[e] += xv * wg[e * D_DIM + i];
    }
#pragma unroll
    for (int e = 0; e < E_NUM; e++) {
#pragma unroll
      for (int off = 32; off; off >>= 1) acc[e] += __shfl_xor(acc[e], off);
    }
    if (lane == 0) {
      float v[E_NUM];
#pragma unroll
      for (int e = 0; e < E_NUM; e++) v[e] = acc[e] + bg[e];
      int i0 = 0; float v0 = v[0];
#pragma unroll
      for (int e = 1; e < E_NUM; e++) if (v[e] > v0) { v0 = v[e]; i0 = e; }
      int i1 = -1; float v1 = -1e30f;
#pragma unroll
      for (int e = 0; e < E_NUM; e++) if (e != i0 && v[e] > v1) { v1 = v[e]; i1 = e; }
      float g0 = 1.f / (1.f + expf(v1 - v0));
      float g1 = 1.f - g0;
      tidx[2 * tok] = i0; tidx[2 * tok + 1] = i1;
      tgate[2 * tok] = g0; tgate[2 * tok + 1] = g1;
      atomicAdd(cnt + i0, 1);
      atomicAdd(cnt + i1, 1);
    }
  } else if (b < 10240) {
    // ---- x fp32 -> bf16 ----
    int i = ((b - 2048) * 256 + tid) * 4;
    float4 v = *(const float4*)(x + i);
    us4 o;
    o[0] = f2bf(v.x); o[1] = f2bf(v.y); o[2] = f2bf(v.z); o[3] = f2bf(v.w);
    *(us4*)(xb + i) = o;
  } else {
    // ---- weight transpose: w1 (E,D,H)->(E,H,D), w2 (E,H,D)->(E,D,H), bf16 ----
    int lb = b - 10240;
    int which = lb >> 15;          // 0: w1 (32768 blocks), 1: w2
    lb &= 32767;
    int e = lb >> 12;
    int local = lb & 4095;
    int rows = which ? H_DIM : D_DIM;
    int cols = which ? D_DIM : H_DIM;
    int xt = which ? (local & 31) : (local & 127);
    int yt = which ? (local >> 5) : (local >> 7);
    const float* ine = (which ? w2 : w1) + (size_t)e * D_DIM * H_DIM;
    unsigned short* oute = (which ? w2t : w1t) + (size_t)e * D_DIM * H_DIM;
    int c0 = xt * 32, r0 = yt * 32;
    int tx = tid & 31, ty = tid >> 5;  // 32 x 8
#pragma unroll
    for (int j = 0; j < 32; j += 8)
      t[ty + j][tx] = ine[(size_t)(r0 + ty + j) * cols + c0 + tx];
    __syncthreads();
#pragma unroll
    for (int j = 0; j < 32; j += 8)
      oute[(size_t)(c0 + ty + j) * rows + r0 + tx] = f2bf(t[tx][ty + j]);
  }
}

// meta: cnt[8] @0 | eoff[9] @8 | cursor[8] @17 | toff1[9] @25 | toff2[9] @34
__global__ void k_prefix(int* __restrict__ meta) {
  if (threadIdx.x == 0) {
    int* cnt = meta;
    int* eoff = meta + 8;
    int* cursor = meta + 17;
    int* toff1 = meta + 25;
    int* toff2 = meta + 34;
    int a = 0, t1 = 0, t2 = 0;
    for (int e = 0; e < E_NUM; e++) {
      eoff[e] = a; cursor[e] = a; a += cnt[e];
      toff1[e] = t1; toff2[e] = t2;
      int mc = (cnt[e] + 127) >> 7;   // ceil(cnt/128): 128-row M-tiles
      t1 += mc * (H_DIM / 128);
      t2 += mc * (D_DIM / 128);
    }
    eoff[E_NUM] = a; toff1[E_NUM] = t1; toff2[E_NUM] = t2;
  }
}

__global__ void k_scatter(const int* __restrict__ tidx, const float* __restrict__ tgate,
                          int* __restrict__ cursor, int* __restrict__ ptok,
                          float* __restrict__ pgate) {
  int t = blockIdx.x * 256 + threadIdx.x;
#pragma unroll
  for (int k = 0; k < 2; k++) {
    int e = tidx[2 * t + k];
    int p = atomicAdd(cursor + e, 1);
    ptok[p] = t;
    pgate[p] = tgate[2 * t + k];
  }
}

// -- grouped GEMM, 128x128 tile, BK=32, ring-3 SINGLE-barrier schedule ------
// R10 geometry (proven best: 72 VGPR + 64 AGPR, 48 KB LDS, 3 blocks/CU,
// 0 bank conflicts) with the two-barrier STEP collapsed to one:
//   step t: vmcnt(4) -> barrier -> STAGE buf (t+2)%3 (= buf (t-1)%3, whose
//   readers all finished before this barrier: their lgkm0+MFMA preceded it)
//   -> 8 frag ds_reads (buf t%3) -> lgkm0 -> setprio(1) 16 MFMA setprio(0).
// Stage-ahead = 2 steps; steady outstanding = 8 loads, own 4 must land -> VM4.
// Seg-swizzle slot[row][s] = data[row][s ^ ((row>>1)&3)] via pre-swizzled
// global source. Compacted tile list via toff prefix; XCD chunk swizzle.
// MODE 1: A = xb gathered via ptok, out = relu(A@B^T + b1) -> Hbuf (bf16)
// MODE 2: A = Hbuf rows direct,   out = (A@B^T + b2)*gate atomicAdd-> Out
template <int KDIM, int NDIM, int MODE>
__global__ __launch_bounds__(256, 3) void k_gemm(
    const unsigned short* __restrict__ A, const unsigned short* __restrict__ Bt,
    const float* __restrict__ bias, const int* __restrict__ meta,
    const int* __restrict__ ptok, const float* __restrict__ pgate,
    unsigned short* __restrict__ Hout, float* __restrict__ Out) {
  constexpr int NT = NDIM / 128;
  constexpr int NKT = KDIM / 32;
  static_assert(NKT % 3 == 2 && NKT >= 8, "tail pattern requires NKT==2 mod 3");
  const int* eoff = meta + 8;
  const int* toff = (MODE == 1) ? (meta + 25) : (meta + 34);

  int tf[E_NUM + 1];
#pragma unroll
  for (int q = 0; q <= E_NUM; q++) tf[q] = RF(toff[q]);

  int nwg = gridDim.x;
  int bid = blockIdx.x;
  int i = (bid & 7) * (nwg >> 3) + (bid >> 3);  // XCD chunk swizzle (nwg%8==0)
  if (i >= tf[E_NUM]) return;                   // few trailing dead tiles
  int e = 0;
#pragma unroll
  for (int q = 1; q < E_NUM; q++) e += (i >= tf[q]);
  int r = i - tf[e];
  int mt = r / NT;
  int nt = r - mt * NT;
  int off = RF(eoff[e]);
  int cnt = RF(eoff[e + 1]) - off;
  int m0 = mt * 128;                            // m0 < cnt by construction

  __shared__ unsigned short lds[3][2][128 * 32];  // 48 KB

  int tid = threadIdx.x;
  int w = tid >> 6, lane = tid & 63;
  int wm = w >> 1, wn = w & 1;  // 2x2 wave grid; per-wave output 64x64

  // staging: chunk q = w*2+c covers rows q*16..q*16+15; lane -> row
  // q*16+(lane>>2), slot seg (lane&3); LDS offset q*512 + lane*8 shorts.
  // Pre-swizzled global seg: (lane&3) ^ ((row>>1)&3) = (lane&3)^((lane>>3)&3).
  int sseg = (lane & 3) ^ ((lane >> 3) & 3);
  const unsigned short* aSrc[2];
  const unsigned short* bSrc[2];
#pragma unroll
  for (int c = 0; c < 2; c++) {
    int q = w * 2 + c;
    int lrow = q * 16 + (lane >> 2);
    int arow = m0 + lrow;
    int ar = (arow < cnt) ? arow : (cnt - 1);
    size_t grow;
    if (MODE == 1) grow = (size_t)ptok[off + ar];
    else grow = (size_t)(off + ar);
    aSrc[c] = A + grow * KDIM + sseg * 8;
    int nrow = nt * 128 + q * 16 + (lane >> 2);
    bSrc[c] = Bt + (size_t)e * NDIM * KDIM + (size_t)nrow * KDIM + sseg * 8;
  }

  // frag reads: row = base + (lane&15); wanted seg = lane>>4;
  // slot seg' = (lane>>4) ^ ((row>>1)&3) = (lane>>4) ^ ((lane>>1)&3).
  int segp = (lane >> 4) ^ ((lane >> 1) & 3);
  f32x4 acc[4][4] = {};

#define STAGE(buf, k0)                                          \
  {                                                             \
    _Pragma("unroll")                                           \
    for (int c = 0; c < 2; c++) {                               \
      int q = w * 2 + c;                                        \
      gload16(aSrc[c] + (k0), &lds[buf][0][q * 512]);           \
      gload16(bSrc[c] + (k0), &lds[buf][1][q * 512]);           \
    }                                                           \
  }
#define NOSTG ((void)0)

#define STEP(buf, WAITC, STGC)                                              \
  {                                                                         \
    WAITC; BARRIER();                                                       \
    STGC;                                                                   \
    bf16x8 aF[4], bF[4];                                                    \
    _Pragma("unroll")                                                       \
    for (int m = 0; m < 4; m++) {                                           \
      int row = wm * 64 + m * 16 + (lane & 15);                             \
      aF[m] = *(const bf16x8*)&lds[buf][0][row * 32 + segp * 8];            \
    }                                                                       \
    _Pragma("unroll")                                                       \
    for (int n = 0; n < 4; n++) {                                           \
      int row = wn * 64 + n * 16 + (lane & 15);                             \
      bF[n] = *(const bf16x8*)&lds[buf][1][row * 32 + segp * 8];            \
    }                                                                       \
    LGKM0;                                                                  \
    __builtin_amdgcn_s_setprio(1);                                          \
    _Pragma("unroll")                                                       \
    for (int m = 0; m < 4; m++)                                             \
      _Pragma("unroll")                                                     \
      for (int n = 0; n < 4; n++)                                           \
        acc[m][n] =                                                         \
            __builtin_amdgcn_mfma_f32_16x16x32_bf16(aF[m], bF[n], acc[m][n], 0, 0, 0); \
    __builtin_amdgcn_s_setprio(0);                                          \
  }

  // prologue: 2 K-steps in flight (8 loads per thread)
  STAGE(0, 0);
  STAGE(1, 32);

  // steps 0..NKT-6 in triples (NKT==2 mod 3); step t stages step t+2
#pragma unroll 1
  for (int kt = 0; kt < NKT - 5; kt += 3) {
    STEP(0, VM4, STAGE(2, (kt + 2) * 32));
    STEP(1, VM4, STAGE(0, (kt + 3) * 32));
    STEP(2, VM4, STAGE(1, (kt + 4) * 32));
  }
  // tail: steps NKT-5 .. NKT-1 (bufs 0,1,2,0,1)
  STEP(0, VM4, STAGE(2, (NKT - 3) * 32));
  STEP(1, VM4, STAGE(0, (NKT - 2) * 32));
  STEP(2, VM4, STAGE(1, (NKT - 1) * 32));
  STEP(0, VM4, NOSTG);
  STEP(1, VM0, NOSTG);

#undef STAGE
#undef NOSTG
#undef STEP

  // epilogue: C/D map col=lane&15, row=(lane>>4)*4+r
#pragma unroll
  for (int m = 0; m < 4; m++) {
    int lrowb = wm * 64 + m * 16 + (lane >> 4) * 4;
#pragma unroll
    for (int r2 = 0; r2 < 4; r2++) {
      int arow = m0 + lrowb + r2;
      if (arow < cnt) {
        if constexpr (MODE == 1) {
          size_t rowbase = (size_t)(off + arow) * NDIM;
#pragma unroll
          for (int n = 0; n < 4; n++) {
            int col = nt * 128 + wn * 64 + n * 16 + (lane & 15);
            float v = acc[m][n][r2] + bias[e * NDIM + col];
            v = v > 0.f ? v : 0.f;
            Hout[rowbase + col] = f2bf(v);
          }
        } else {
          int tok = ptok[off + arow];
          float g = pgate[off + arow];
#pragma unroll
          for (int n = 0; n < 4; n++) {
            int col = nt * 128 + wn * 64 + n * 16 + (lane & 15);
            float v = (acc[m][n][r2] + bias[e * NDIM + col]) * g;
            atomicAdd(Out + (size_t)tok * D_DIM + col, v);
          }
        }
      }
    }
  }
}

extern "C" void kernel_launch(void* const* d_in, const int* in_sizes, int n_in,
                              void* d_out, int out_size, void* d_ws, size_t ws_size,
                              hipStream_t stream) {
  const float* x  = (const float*)d_in[0];
  const float* wg = (const float*)d_in[1];
  const float* bg = (const float*)d_in[2];
  const float* w1 = (const float*)d_in[3];
  const float* b1 = (const float*)d_in[4];
  const float* w2 = (const float*)d_in[5];
  const float* b2 = (const float*)d_in[6];
  float* out = (float*)d_out;

  char* ws = (char*)d_ws;
  unsigned short* xb = (unsigned short*)ws;   ws += (size_t)B_TOK * D_DIM * 2;
  unsigned short* w1t = (unsigned short*)ws;  ws += (size_t)E_NUM * D_DIM * H_DIM * 2;
  unsigned short* w2t = (unsigned short*)ws;  ws += (size_t)E_NUM * D_DIM * H_DIM * 2;
  unsigned short* Hbuf = (unsigned short*)ws; ws += (size_t)NPAIR * H_DIM * 2;
  int* tidx = (int*)ws;    ws += (size_t)NPAIR * 4;
  float* tgate = (float*)ws; ws += (size_t)NPAIR * 4;
  int* ptok = (int*)ws;    ws += (size_t)NPAIR * 4;
  float* pgate = (float*)ws; ws += (size_t)NPAIR * 4;
  int* meta = (int*)ws;  // cnt[8] | eoff[9] | cursor[8] | toff1[9] | toff2[9]
  int* cursor = meta + 17;

  hipMemsetAsync(meta, 0, 64 * sizeof(int), stream);
  hipMemsetAsync(out, 0, (size_t)out_size * sizeof(float), stream);

  // fused prep: router (2048) + convert_x (8192) + w transposes (65536)
  k_prep<<<2048 + 8192 + 65536, 256, 0, stream>>>(
      x, xb, w1, w2, w1t, w2t, wg, bg, tidx, tgate, meta);
  k_prefix<<<1, 64, 0, stream>>>(meta);
  k_scatter<<<B_TOK / 256, 256, 0, stream>>>(tidx, tgate, cursor, ptok, pgate);
  // worst-case compact grids (host consts, divisible by 8):
  // G1 = (NPAIR/128 + E) * (H/128) = 136*32 = 4352
  // G2 = (NPAIR/128 + E) * (D/128) = 136*8  = 1088
  k_gemm<D_DIM, H_DIM, 1><<<(NPAIR / 128 + E_NUM) * (H_DIM / 128), 256, 0, stream>>>(
      xb, w1t, b1, meta, ptok, pgate, Hbuf, nullptr);
  k_gemm<H_DIM, D_DIM, 2><<<(NPAIR / 128 + E_NUM) * (D_DIM / 128), 256, 0, stream>>>(
      Hbuf, w2t, b2, meta, ptok, pgate, nullptr, out);
}

// Round 14
// 808.031 us; speedup vs baseline: 1.0539x; 1.0082x over previous
//
#include <hip/hip_runtime.h>
#include <hip/hip_bf16.h>
#include <math.h>

#define B_TOK 8192
#define D_DIM 1024
#define H_DIM 4096
#define E_NUM 8
#define NPAIR (B_TOK * 2)

typedef __bf16 bf16x8 __attribute__((ext_vector_type(8)));
typedef float f32x4 __attribute__((ext_vector_type(4)));
typedef unsigned short us4 __attribute__((ext_vector_type(4)));
typedef unsigned short us8 __attribute__((ext_vector_type(8)));

__device__ __forceinline__ unsigned short f2bf(float f) {
  union { float f; unsigned u; } v; v.f = f;
  unsigned r = v.u + 0x7FFFu + ((v.u >> 16) & 1u);
  return (unsigned short)(r >> 16);
}

__device__ __forceinline__ void gload16(const void* g, void* l) {
  __builtin_amdgcn_global_load_lds(
      (const __attribute__((address_space(1))) void*)g,
      (__attribute__((address_space(3))) void*)l, 16, 0, 0);
}

#define BARRIER()    asm volatile("s_barrier" ::: "memory")
#define VM4          asm volatile("s_waitcnt vmcnt(4)" ::: "memory")
#define VM0          asm volatile("s_waitcnt vmcnt(0)" ::: "memory")
#define LGKM0        asm volatile("s_waitcnt lgkmcnt(0)" ::: "memory")
#define RF(x) __builtin_amdgcn_readfirstlane(x)

// -- fused prep: router [0,2048) | x->bf16 [2048,10240) | w-transp [10240,26624)
// Transpose path (R14): 64x64 tiles, 16 coalesced scalar loads hoisted to
// regs -> bf16 -> us4 LDS writes ([64][68] pad: 4-way write alias, free
// 2-way read) -> us8 (16B) coalesced global writes. Was: scalar everything
// at VGPR=16 -> 297 us, 7% HBM (R13 profile).
__global__ void k_prep(const float* __restrict__ x, unsigned short* __restrict__ xb,
                       const float* __restrict__ w1, const float* __restrict__ w2,
                       unsigned short* __restrict__ w1t, unsigned short* __restrict__ w2t,
                       const float* __restrict__ wg, const float* __restrict__ bg,
                       int* __restrict__ tidx, float* __restrict__ tgate,
                       int* __restrict__ cnt) {
  __shared__ unsigned short tl[64][68];
  int b = blockIdx.x;
  int tid = threadIdx.x;
  if (b < 2048) {
    // ---- router: 4 tokens per block ----
    int wid = tid >> 6, lane = tid & 63;
    int tok = b * 4 + wid;
    float acc[E_NUM];
#pragma unroll
    for (int e = 0; e < E_NUM; e++) acc[e] = 0.f;
    const float* xr = x + (size_t)tok * D_DIM;
    for (int i = lane; i < D_DIM; i += 64) {
      float xv = xr[i];
#pragma unroll
      for (int e = 0; e < E_NUM; e++) acc[e] += xv * wg[e * D_DIM + i];
    }
#pragma unroll
    for (int e = 0; e < E_NUM; e++) {
#pragma unroll
      for (int off = 32; off; off >>= 1) acc[e] += __shfl_xor(acc[e], off);
    }
    if (lane == 0) {
      float v[E_NUM];
#pragma unroll
      for (int e = 0; e < E_NUM; e++) v[e] = acc[e] + bg[e];
      int i0 = 0; float v0 = v[0];
#pragma unroll
      for (int e = 1; e < E_NUM; e++) if (v[e] > v0) { v0 = v[e]; i0 = e; }
      int i1 = -1; float v1 = -1e30f;
#pragma unroll
      for (int e = 0; e < E_NUM; e++) if (e != i0 && v[e] > v1) { v1 = v[e]; i1 = e; }
      float g0 = 1.f / (1.f + expf(v1 - v0));
      float g1 = 1.f - g0;
      tidx[2 * tok] = i0; tidx[2 * tok + 1] = i1;
      tgate[2 * tok] = g0; tgate[2 * tok + 1] = g1;
      atomicAdd(cnt + i0, 1);
      atomicAdd(cnt + i1, 1);
    }
  } else if (b < 10240) {
    // ---- x fp32 -> bf16 ----
    int i = ((b - 2048) * 256 + tid) * 4;
    float4 v = *(const float4*)(x + i);
    us4 o;
    o[0] = f2bf(v.x); o[1] = f2bf(v.y); o[2] = f2bf(v.z); o[3] = f2bf(v.w);
    *(us4*)(xb + i) = o;
  } else {
    // ---- weight transpose: M[R][C] fp32 -> T[C][R] bf16, 64x64 tile ----
    // w1 (which=0): M = w1[e] (D x H) -> w1t (H x D)
    // w2 (which=1): M = w2[e] (H x D) -> w2t (D x H)
    int lb = b - 10240;            // 0..16383
    int which = lb >> 13;          // 8192 blocks per tensor
    int rem = lb & 8191;
    int e = rem >> 10;             // 1024 tiles per expert
    int local = rem & 1023;
    int R = which ? H_DIM : D_DIM;
    int C = which ? D_DIM : H_DIM;
    int RT = which ? (H_DIM / 64) : (D_DIM / 64);
    int rt = local & (RT - 1);
    int ct = local / RT;
    const float* ine = (which ? w2 : w1) + (size_t)e * D_DIM * H_DIM;
    unsigned short* oute = (which ? w2t : w1t) + (size_t)e * D_DIM * H_DIM;
    int r0 = rt * 64, c0 = ct * 64;
    int cin = tid & 63;            // column within tile (coalesced per wave)
    int rgrp = tid >> 6;           // 0..3

    // 16 coalesced scalar loads, hoisted for ILP
    float v[4][4];
#pragma unroll
    for (int it = 0; it < 4; ++it)
#pragma unroll
      for (int j = 0; j < 4; ++j)
        v[it][j] = ine[(size_t)(r0 + it * 16 + rgrp * 4 + j) * C + c0 + cin];
    // convert + vector LDS writes: tl[c][r], us4 along r
#pragma unroll
    for (int it = 0; it < 4; ++it) {
      us4 o;
#pragma unroll
      for (int j = 0; j < 4; ++j) o[j] = f2bf(v[it][j]);
      *(us4*)&tl[cin][it * 16 + rgrp * 4] = o;
    }
    __syncthreads();
    // coalesced 16B global writes: 8 lanes cover one 128B output row segment
#pragma unroll
    for (int wt = 0; wt < 2; ++wt) {
      int cc = wt * 32 + (tid >> 3);
      int g = tid & 7;
      us4 lo = *(const us4*)&tl[cc][g * 8];
      us4 hi = *(const us4*)&tl[cc][g * 8 + 4];
      us8 o8 = {lo[0], lo[1], lo[2], lo[3], hi[0], hi[1], hi[2], hi[3]};
      *(us8*)&oute[(size_t)(c0 + cc) * R + r0 + g * 8] = o8;
    }
  }
}

// meta: cnt[8] @0 | eoff[9] @8 | cursor[8] @17 | toff1[9] @25 | toff2[9] @34
__global__ void k_prefix(int* __restrict__ meta) {
  if (threadIdx.x == 0) {
    int* cnt = meta;
    int* eoff = meta + 8;
    int* cursor = meta + 17;
    int* toff1 = meta + 25;
    int* toff2 = meta + 34;
    int a = 0, t1 = 0, t2 = 0;
    for (int e = 0; e < E_NUM; e++) {
      eoff[e] = a; cursor[e] = a; a += cnt[e];
      toff1[e] = t1; toff2[e] = t2;
      int mc = (cnt[e] + 127) >> 7;   // ceil(cnt/128): 128-row M-tiles
      t1 += mc * (H_DIM / 128);
      t2 += mc * (D_DIM / 128);
    }
    eoff[E_NUM] = a; toff1[E_NUM] = t1; toff2[E_NUM] = t2;
  }
}

__global__ void k_scatter(const int* __restrict__ tidx, const float* __restrict__ tgate,
                          int* __restrict__ cursor, int* __restrict__ ptok,
                          float* __restrict__ pgate) {
  int t = blockIdx.x * 256 + threadIdx.x;
#pragma unroll
  for (int k = 0; k < 2; k++) {
    int e = tidx[2 * t + k];
    int p = atomicAdd(cursor + e, 1);
    ptok[p] = t;
    pgate[p] = tgate[2 * t + k];
  }
}

// -- grouped GEMM, 128x128 tile, BK=32, ring-3 SINGLE-barrier schedule ------
// (unchanged from R13 — proven: 72 VGPR + 64 AGPR, 48 KB LDS, 3 blocks/CU,
// 0 bank conflicts, one barrier + one counted vmcnt per K-step)
//   step t: vmcnt(4) -> barrier -> STAGE buf (t+2)%3 (readers of that buf
//   finished before this barrier) -> 8 frag ds_reads (buf t%3) -> lgkm0 ->
//   setprio(1) 16 MFMA setprio(0).
// MODE 1: A = xb gathered via ptok, out = relu(A@B^T + b1) -> Hbuf (bf16)
// MODE 2: A = Hbuf rows direct,   out = (A@B^T + b2)*gate atomicAdd-> Out
template <int KDIM, int NDIM, int MODE>
__global__ __launch_bounds__(256, 3) void k_gemm(
    const unsigned short* __restrict__ A, const unsigned short* __restrict__ Bt,
    const float* __restrict__ bias, const int* __restrict__ meta,
    const int* __restrict__ ptok, const float* __restrict__ pgate,
    unsigned short* __restrict__ Hout, float* __restrict__ Out) {
  constexpr int NT = NDIM / 128;
  constexpr int NKT = KDIM / 32;
  static_assert(NKT % 3 == 2 && NKT >= 8, "tail pattern requires NKT==2 mod 3");
  const int* eoff = meta + 8;
  const int* toff = (MODE == 1) ? (meta + 25) : (meta + 34);

  int tf[E_NUM + 1];
#pragma unroll
  for (int q = 0; q <= E_NUM; q++) tf[q] = RF(toff[q]);

  int nwg = gridDim.x;
  int bid = blockIdx.x;
  int i = (bid & 7) * (nwg >> 3) + (bid >> 3);  // XCD chunk swizzle (nwg%8==0)
  if (i >= tf[E_NUM]) return;                   // few trailing dead tiles
  int e = 0;
#pragma unroll
  for (int q = 1; q < E_NUM; q++) e += (i >= tf[q]);
  int r = i - tf[e];
  int mt = r / NT;
  int nt = r - mt * NT;
  int off = RF(eoff[e]);
  int cnt = RF(eoff[e + 1]) - off;
  int m0 = mt * 128;                            // m0 < cnt by construction

  __shared__ unsigned short lds[3][2][128 * 32];  // 48 KB

  int tid = threadIdx.x;
  int w = tid >> 6, lane = tid & 63;
  int wm = w >> 1, wn = w & 1;  // 2x2 wave grid; per-wave output 64x64

  int sseg = (lane & 3) ^ ((lane >> 3) & 3);
  const unsigned short* aSrc[2];
  const unsigned short* bSrc[2];
#pragma unroll
  for (int c = 0; c < 2; c++) {
    int q = w * 2 + c;
    int lrow = q * 16 + (lane >> 2);
    int arow = m0 + lrow;
    int ar = (arow < cnt) ? arow : (cnt - 1);
    size_t grow;
    if (MODE == 1) grow = (size_t)ptok[off + ar];
    else grow = (size_t)(off + ar);
    aSrc[c] = A + grow * KDIM + sseg * 8;
    int nrow = nt * 128 + q * 16 + (lane >> 2);
    bSrc[c] = Bt + (size_t)e * NDIM * KDIM + (size_t)nrow * KDIM + sseg * 8;
  }

  int segp = (lane >> 4) ^ ((lane >> 1) & 3);
  f32x4 acc[4][4] = {};

#define STAGE(buf, k0)                                          \
  {                                                             \
    _Pragma("unroll")                                           \
    for (int c = 0; c < 2; c++) {                               \
      int q = w * 2 + c;                                        \
      gload16(aSrc[c] + (k0), &lds[buf][0][q * 512]);           \
      gload16(bSrc[c] + (k0), &lds[buf][1][q * 512]);           \
    }                                                           \
  }
#define NOSTG ((void)0)

#define STEP(buf, WAITC, STGC)                                              \
  {                                                                         \
    WAITC; BARRIER();                                                       \
    STGC;                                                                   \
    bf16x8 aF[4], bF[4];                                                    \
    _Pragma("unroll")                                                       \
    for (int m = 0; m < 4; m++) {                                           \
      int row = wm * 64 + m * 16 + (lane & 15);                             \
      aF[m] = *(const bf16x8*)&lds[buf][0][row * 32 + segp * 8];            \
    }                                                                       \
    _Pragma("unroll")                                                       \
    for (int n = 0; n < 4; n++) {                                           \
      int row = wn * 64 + n * 16 + (lane & 15);                             \
      bF[n] = *(const bf16x8*)&lds[buf][1][row * 32 + segp * 8];            \
    }                                                                       \
    LGKM0;                                                                  \
    __builtin_amdgcn_s_setprio(1);                                          \
    _Pragma("unroll")                                                       \
    for (int m = 0; m < 4; m++)                                             \
      _Pragma("unroll")                                                     \
      for (int n = 0; n < 4; n++)                                           \
        acc[m][n] =                                                         \
            __builtin_amdgcn_mfma_f32_16x16x32_bf16(aF[m], bF[n], acc[m][n], 0, 0, 0); \
    __builtin_amdgcn_s_setprio(0);                                          \
  }

  STAGE(0, 0);
  STAGE(1, 32);

#pragma unroll 1
  for (int kt = 0; kt < NKT - 5; kt += 3) {
    STEP(0, VM4, STAGE(2, (kt + 2) * 32));
    STEP(1, VM4, STAGE(0, (kt + 3) * 32));
    STEP(2, VM4, STAGE(1, (kt + 4) * 32));
  }
  STEP(0, VM4, STAGE(2, (NKT - 3) * 32));
  STEP(1, VM4, STAGE(0, (NKT - 2) * 32));
  STEP(2, VM4, STAGE(1, (NKT - 1) * 32));
  STEP(0, VM4, NOSTG);
  STEP(1, VM0, NOSTG);

#undef STAGE
#undef NOSTG
#undef STEP

  // epilogue: C/D map col=lane&15, row=(lane>>4)*4+r
#pragma unroll
  for (int m = 0; m < 4; m++) {
    int lrowb = wm * 64 + m * 16 + (lane >> 4) * 4;
#pragma unroll
    for (int r2 = 0; r2 < 4; r2++) {
      int arow = m0 + lrowb + r2;
      if (arow < cnt) {
        if constexpr (MODE == 1) {
          size_t rowbase = (size_t)(off + arow) * NDIM;
#pragma unroll
          for (int n = 0; n < 4; n++) {
            int col = nt * 128 + wn * 64 + n * 16 + (lane & 15);
            float v = acc[m][n][r2] + bias[e * NDIM + col];
            v = v > 0.f ? v : 0.f;
            Hout[rowbase + col] = f2bf(v);
          }
        } else {
          int tok = ptok[off + arow];
          float g = pgate[off + arow];
#pragma unroll
          for (int n = 0; n < 4; n++) {
            int col = nt * 128 + wn * 64 + n * 16 + (lane & 15);
            float v = (acc[m][n][r2] + bias[e * NDIM + col]) * g;
            atomicAdd(Out + (size_t)tok * D_DIM + col, v);
          }
        }
      }
    }
  }
}

extern "C" void kernel_launch(void* const* d_in, const int* in_sizes, int n_in,
                              void* d_out, int out_size, void* d_ws, size_t ws_size,
                              hipStream_t stream) {
  const float* x  = (const float*)d_in[0];
  const float* wg = (const float*)d_in[1];
  const float* bg = (const float*)d_in[2];
  const float* w1 = (const float*)d_in[3];
  const float* b1 = (const float*)d_in[4];
  const float* w2 = (const float*)d_in[5];
  const float* b2 = (const float*)d_in[6];
  float* out = (float*)d_out;

  char* ws = (char*)d_ws;
  unsigned short* xb = (unsigned short*)ws;   ws += (size_t)B_TOK * D_DIM * 2;
  unsigned short* w1t = (unsigned short*)ws;  ws += (size_t)E_NUM * D_DIM * H_DIM * 2;
  unsigned short* w2t = (unsigned short*)ws;  ws += (size_t)E_NUM * D_DIM * H_DIM * 2;
  unsigned short* Hbuf = (unsigned short*)ws; ws += (size_t)NPAIR * H_DIM * 2;
  int* tidx = (int*)ws;    ws += (size_t)NPAIR * 4;
  float* tgate = (float*)ws; ws += (size_t)NPAIR * 4;
  int* ptok = (int*)ws;    ws += (size_t)NPAIR * 4;
  float* pgate = (float*)ws; ws += (size_t)NPAIR * 4;
  int* meta = (int*)ws;  // cnt[8] | eoff[9] | cursor[8] | toff1[9] | toff2[9]
  int* cursor = meta + 17;

  hipMemsetAsync(meta, 0, 64 * sizeof(int), stream);
  hipMemsetAsync(out, 0, (size_t)out_size * sizeof(float), stream);

  // fused prep: router (2048) + convert_x (8192) + w transposes (16384)
  k_prep<<<2048 + 8192 + 16384, 256, 0, stream>>>(
      x, xb, w1, w2, w1t, w2t, wg, bg, tidx, tgate, meta);
  k_prefix<<<1, 64, 0, stream>>>(meta);
  k_scatter<<<B_TOK / 256, 256, 0, stream>>>(tidx, tgate, cursor, ptok, pgate);
  // worst-case compact grids (host consts, divisible by 8):
  // G1 = (NPAIR/128 + E) * (H/128) = 136*32 = 4352
  // G2 = (NPAIR/128 + E) * (D/128) = 136*8  = 1088
  k_gemm<D_DIM, H_DIM, 1><<<(NPAIR / 128 + E_NUM) * (H_DIM / 128), 256, 0, stream>>>(
      xb, w1t, b1, meta, ptok, pgate, Hbuf, nullptr);
  k_gemm<H_DIM, D_DIM, 2><<<(NPAIR / 128 + E_NUM) * (D_DIM / 128), 256, 0, stream>>>(
      Hbuf, w2t, b2, meta, ptok, pgate, nullptr, out);
}